// Round 1
// baseline (64.594 us; speedup 1.0000x reference)
//
#include <hip/hip_runtime.h>
#include <math.h>

// KANLinear forward, MI355X.
// out[b,i,o] = silu( (x@W)[b,o] + sum_k basis[b,i,k] * sw[i,o,k] )
// b=1024, i=256, o=256, k=7 (grid_size=5, order=3). Output 268MB f32 -> write-bound.

#define B_TOT 1024
#define NF 256

__device__ __forceinline__ float silu_f(float z) {
    float e = __expf(-z);
    return z * __builtin_amdgcn_rcpf(1.0f + e);
}

// ---------------- Kernel 1: base_out = x @ W  (1024x256 @ 256x256) ----------------
__global__ __launch_bounds__(256) void base_gemm(const float* __restrict__ x,
                                                 const float* __restrict__ W,
                                                 float* __restrict__ base) {
    __shared__ float xs[2][NF];
    const int b0 = blockIdx.x * 2;
    const int t = threadIdx.x;
    xs[0][t] = x[(b0 + 0) * NF + t];
    xs[1][t] = x[(b0 + 1) * NF + t];
    __syncthreads();
    float acc0 = 0.f, acc1 = 0.f;
#pragma unroll 8
    for (int k = 0; k < NF; ++k) {
        float w = W[k * NF + t];
        acc0 += xs[0][k] * w;
        acc1 += xs[1][k] * w;
    }
    base[(b0 + 0) * NF + t] = acc0;
    base[(b0 + 1) * NF + t] = acc1;
}

// ---------------- Kernel 2: fused basis + spline einsum + silu ----------------
// grid: (16 i-chunks, 64 b-chunks); block 256 threads.
// Per block: BCH=16 batch rows, ICH=16 input features.
__global__ __launch_bounds__(256) void kan_main(const float* __restrict__ x,
                                                const float* __restrict__ sw,
                                                const float* __restrict__ grid,
                                                const float* __restrict__ base,
                                                float* __restrict__ out) {
    const int i0 = blockIdx.x * 16;
    const int b0 = blockIdx.y * 16;
    const int tid = threadIdx.x;

    __shared__ float bas[16][16][8]; // [ii][bb][k], 8KB, k padded to 8

    // ---- Phase A: each thread computes the 7-basis for one (bb, ii) pair ----
    {
        const int ii = tid & 15;
        const int bb = tid >> 4;
        const int gi = i0 + ii;
        const float xv = x[(b0 + bb) * NF + gi];
        const float g0 = grid[0 * NF + gi];
        const float g1 = grid[1 * NF + gi];
        const float g2 = grid[2 * NF + gi];
        const float g3 = grid[3 * NF + gi];
        const float g4 = grid[4 * NF + gi];
        const float L = 2.f * g0 - g3;
        const float R = 2.f * g4 - g1;
        float eg[11] = {L, L, L, g0, g1, g2, g3, g4, R, R, R};

        float B0[10];
#pragma unroll
        for (int t = 0; t < 10; ++t)
            B0[t] = (xv >= eg[t] && xv < eg[t + 1]) ? 1.f : 0.f;

        float B1[9];
#pragma unroll
        for (int t = 0; t < 9; ++t) {
            float dl = eg[t + 1] - eg[t];
            float dr = eg[t + 2] - eg[t + 1];
            float lt = (dl != 0.f) ? (xv - eg[t]) / dl : 0.f;
            float rt = (dr != 0.f) ? (eg[t + 2] - xv) / dr : 0.f;
            B1[t] = lt * B0[t] + rt * B0[t + 1];
        }
        float B2[8];
#pragma unroll
        for (int t = 0; t < 8; ++t) {
            float dl = eg[t + 2] - eg[t];
            float dr = eg[t + 3] - eg[t + 1];
            float lt = (dl != 0.f) ? (xv - eg[t]) / dl : 0.f;
            float rt = (dr != 0.f) ? (eg[t + 3] - xv) / dr : 0.f;
            B2[t] = lt * B1[t] + rt * B1[t + 1];
        }
#pragma unroll
        for (int k = 0; k < 7; ++k) bas[ii][bb][k] = B2[k];
        bas[ii][bb][7] = 0.f;
    }

    // ---- Load base rows into registers: br[bb] = base[b0+bb][lane*4 .. +3] ----
    const int lane = tid & 63;
    const int wv = tid >> 6; // wave id 0..3
    float4 br[16];
#pragma unroll
    for (int bb = 0; bb < 16; ++bb)
        br[bb] = *reinterpret_cast<const float4*>(&base[(size_t)(b0 + bb) * NF + lane * 4]);

    __syncthreads();

    // ---- Main: wave wv handles ii = wv*4 + step ----
    for (int step = 0; step < 4; ++step) {
        const int ii = wv * 4 + step;
        const int i = i0 + ii;

        // sw regs: s[oo][k] = sw[i][lane*4+oo][k]
        float s[4][7];
#pragma unroll
        for (int oo = 0; oo < 4; ++oo) {
            const float* p = &sw[((size_t)i * NF + lane * 4 + oo) * 7];
#pragma unroll
            for (int k = 0; k < 7; ++k) s[oo][k] = p[k];
        }

#pragma unroll
        for (int bb = 0; bb < 16; ++bb) {
            float4 bl = *reinterpret_cast<const float4*>(&bas[ii][bb][0]);
            float4 bh = *reinterpret_cast<const float4*>(&bas[ii][bb][4]);
            float bk[7] = {bl.x, bl.y, bl.z, bl.w, bh.x, bh.y, bh.z};
            float a0 = br[bb].x, a1 = br[bb].y, a2 = br[bb].z, a3 = br[bb].w;
#pragma unroll
            for (int k = 0; k < 7; ++k) {
                a0 += bk[k] * s[0][k];
                a1 += bk[k] * s[1][k];
                a2 += bk[k] * s[2][k];
                a3 += bk[k] * s[3][k];
            }
            float4 o4;
            o4.x = silu_f(a0);
            o4.y = silu_f(a1);
            o4.z = silu_f(a2);
            o4.w = silu_f(a3);
            *reinterpret_cast<float4*>(
                &out[((size_t)(b0 + bb) * NF + i) * NF + lane * 4]) = o4;
        }
    }
}

extern "C" void kernel_launch(void* const* d_in, const int* in_sizes, int n_in,
                              void* d_out, int out_size, void* d_ws, size_t ws_size,
                              hipStream_t stream) {
    const float* x    = (const float*)d_in[0]; // (1024, 256)
    const float* bw   = (const float*)d_in[1]; // (256, 256)
    const float* sw   = (const float*)d_in[2]; // (256, 256, 7)
    const float* grid = (const float*)d_in[3]; // (5, 256)
    float* out = (float*)d_out;                // (1024, 256, 256)
    float* base = (float*)d_ws;                // 1 MB scratch for x@W

    base_gemm<<<dim3(512), 256, 0, stream>>>(x, bw, base);
    kan_main<<<dim3(16, 64), 256, 0, stream>>>(x, sw, grid, base, out);
}